// Round 1
// baseline (591.159 us; speedup 1.0000x reference)
//
#include <hip/hip_runtime.h>

#define B 8
#define K 16
#define H 224
#define W 224
#define PH 232
#define PW 232
#define WIN 9
#define WQ 56              // W / 4 pixels per quad-row
#define NQ (B * H * WQ)    // 100352 quads, exactly 1568 waves of 64

__global__ __launch_bounds__(64) void ncuts_main(
    const float* __restrict__ seg,      // [B][K][H][W]
    const float* __restrict__ padded,   // [B][K][PH][PW]
    const float* __restrict__ weight,   // [B][H][W][9][9]
    const float* __restrict__ sumw,     // [B][H][W]
    float* __restrict__ ws)             // ws[0..127]=A[b][k], ws[128..255]=V[b][k]
{
    const int q = blockIdx.x * 64 + threadIdx.x;   // NQ % 64 == 0, no guard needed
    const int wq = q % WQ;
    const int t  = q / WQ;
    const int h  = t % H;
    const int b  = t / H;
    const int w0 = wq * 4;

    float acc[K][4];
#pragma unroll
    for (int k = 0; k < K; ++k)
#pragma unroll
        for (int p = 0; p < 4; ++p) acc[k][p] = 0.f;

    const long pixbase = ((long)(b * H + h)) * W + w0;          // pixel idx of p=0
    const float* wbase = weight + pixbase * 81;                 // 81 wts per pixel
    const float* pbase = padded + ((long)(b * K) * PH + h) * PW + w0;

    // m-loop kept rolled (9 iters) to bound code size; k,p,n fully unrolled.
#pragma unroll 1
    for (int m = 0; m < WIN; ++m) {
        float wr[4][WIN];
#pragma unroll
        for (int p = 0; p < 4; ++p) {
            const float* wp = wbase + (long)p * 81 + m * 9;
#pragma unroll
            for (int n = 0; n < WIN; ++n) wr[p][n] = wp[n];
        }
        const float* prow = pbase + (long)m * PW;
#pragma unroll
        for (int k = 0; k < K; ++k) {
            const float4* pr = (const float4*)(prow + (long)k * PH * PW); // 16B aligned
            float4 a0 = pr[0], a1 = pr[1], a2 = pr[2];
            float win[12] = {a0.x, a0.y, a0.z, a0.w,
                             a1.x, a1.y, a1.z, a1.w,
                             a2.x, a2.y, a2.z, a2.w};
#pragma unroll
            for (int p = 0; p < 4; ++p)
#pragma unroll
                for (int n = 0; n < WIN; ++n)
                    acc[k][p] = fmaf(win[p + n], wr[p][n], acc[k][p]);
        }
    }

    // epilogue: assocA / assocV partials for this quad
    const float4 sw4 = *(const float4*)(sumw + pixbase);
    const float swv[4] = {sw4.x, sw4.y, sw4.z, sw4.w};
    const float* sbase = seg + ((long)(b * K) * H + h) * W + w0;

    float accA[K], accV[K];
#pragma unroll
    for (int k = 0; k < K; ++k) {
        const float4 s4 = *(const float4*)(sbase + (long)k * H * W);
        const float sv[4] = {s4.x, s4.y, s4.z, s4.w};
        float a = 0.f, v = 0.f;
#pragma unroll
        for (int p = 0; p < 4; ++p) {
            a = fmaf(acc[k][p], sv[p], a);
            v = fmaf(swv[p], sv[p], v);
        }
        accA[k] = a;
        accV[k] = v;
    }

    // 64-lane butterfly reduction, then one atomic per (k, {A,V}) per wave
#pragma unroll
    for (int k = 0; k < K; ++k) {
        float a = accA[k], v = accV[k];
#pragma unroll
        for (int off = 32; off > 0; off >>= 1) {
            a += __shfl_xor(a, off);
            v += __shfl_xor(v, off);
        }
        if (threadIdx.x == 0) {
            atomicAdd(&ws[b * K + k], a);
            atomicAdd(&ws[128 + b * K + k], v);
        }
    }
}

__global__ void ncuts_final(const float* __restrict__ ws,
                            const int* __restrict__ ncut_k,
                            float* __restrict__ out)
{
    const int t = threadIdx.x;        // 128 threads: t = b*16 + k
    const int b = t >> 4;
    const int k = t & 15;
    float r = ws[b * K + k] / ws[128 + b * K + k];
#pragma unroll
    for (int off = 1; off < 16; off <<= 1) r += __shfl_xor(r, off, 16);
    if (k == 0) out[b] = (float)(*ncut_k) - r;
}

extern "C" void kernel_launch(void* const* d_in, const int* in_sizes, int n_in,
                              void* d_out, int out_size, void* d_ws, size_t ws_size,
                              hipStream_t stream) {
    (void)in_sizes; (void)n_in; (void)out_size; (void)ws_size;
    const float* seg    = (const float*)d_in[0];
    const float* padded = (const float*)d_in[1];
    const float* weight = (const float*)d_in[2];
    const float* sumw   = (const float*)d_in[3];
    const int*   nk     = (const int*)d_in[5];
    float* ws  = (float*)d_ws;
    float* out = (float*)d_out;

    hipMemsetAsync(ws, 0, 2 * B * K * sizeof(float), stream);
    ncuts_main<<<NQ / 64, 64, 0, stream>>>(seg, padded, weight, sumw, ws);
    ncuts_final<<<1, 128, 0, stream>>>(ws, nk, out);
}

// Round 2
// 506.784 us; speedup vs baseline: 1.1665x; 1.1665x over previous
//
#include <hip/hip_runtime.h>

#define B 8
#define K 16
#define H 224
#define W 224
#define PH 232
#define PW 232
#define WIN 9
#define WQ 56              // W / 4 pixels per quad-row
#define NQ (B * H * WQ)    // 100352 quads
#define BLK 256
#define NB (NQ / BLK)      // 392 blocks; 392/8 = 49 blocks per XCD chunk

__global__ __launch_bounds__(BLK) void ncuts_main(
    const float* __restrict__ seg,      // [B][K][H][W]
    const float* __restrict__ padded,   // [B][K][PH][PW]
    const float* __restrict__ weight,   // [B][H][W][9][9]
    const float* __restrict__ sumw,     // [B][H][W]
    float* __restrict__ ws)             // ws[0..127]=A[b][k], ws[128..255]=V[b][k]
{
    // XCD-locality swizzle: dispatch sends block i to XCD i%8. Remap so XCD x
    // gets the contiguous quad range [x*49*256, (x+1)*49*256) — exactly batch
    // image b=x. All 9 h-neighbors of a padded row then hit the same 4MB L2.
    const int qb = (blockIdx.x & 7) * (NB / 8) + (blockIdx.x >> 3);
    const int q  = qb * BLK + threadIdx.x;
    const int wq = q % WQ;
    const int t  = q / WQ;
    const int h  = t % H;
    const int b  = t / H;
    const int w0 = wq * 4;

    float acc[K][4];
#pragma unroll
    for (int k = 0; k < K; ++k)
#pragma unroll
        for (int p = 0; p < 4; ++p) acc[k][p] = 0.f;

    const long pixbase = ((long)(b * H + h)) * W + w0;          // pixel idx of p=0
    const float* wbase = weight + pixbase * 81;                 // 81 wts per pixel
    const float* pbase = padded + ((long)(b * K) * PH + h) * PW + w0;

    // m-loop kept rolled (9 iters) to bound code size; k,p,n fully unrolled.
#pragma unroll 1
    for (int m = 0; m < WIN; ++m) {
        float wr[4][WIN];
#pragma unroll
        for (int p = 0; p < 4; ++p) {
            const float* wp = wbase + (long)p * 81 + m * 9;
#pragma unroll
            for (int n = 0; n < WIN; ++n) wr[p][n] = wp[n];
        }
        const float* prow = pbase + (long)m * PW;
#pragma unroll
        for (int k = 0; k < K; ++k) {
            const float4* pr = (const float4*)(prow + (long)k * PH * PW); // 16B aligned
            float4 a0 = pr[0], a1 = pr[1], a2 = pr[2];
            float win[12] = {a0.x, a0.y, a0.z, a0.w,
                             a1.x, a1.y, a1.z, a1.w,
                             a2.x, a2.y, a2.z, a2.w};
#pragma unroll
            for (int p = 0; p < 4; ++p)
#pragma unroll
                for (int n = 0; n < WIN; ++n)
                    acc[k][p] = fmaf(win[p + n], wr[p][n], acc[k][p]);
        }
    }

    // epilogue: assocA / assocV partials for this quad
    const float4 sw4 = *(const float4*)(sumw + pixbase);
    const float swv[4] = {sw4.x, sw4.y, sw4.z, sw4.w};
    const float* sbase = seg + ((long)(b * K) * H + h) * W + w0;

    float accA[K], accV[K];
#pragma unroll
    for (int k = 0; k < K; ++k) {
        const float4 s4 = *(const float4*)(sbase + (long)k * H * W);
        const float sv[4] = {s4.x, s4.y, s4.z, s4.w};
        float a = 0.f, v = 0.f;
#pragma unroll
        for (int p = 0; p < 4; ++p) {
            a = fmaf(acc[k][p], sv[p], a);
            v = fmaf(swv[p], sv[p], v);
        }
        accA[k] = a;
        accV[k] = v;
    }

    // per-wave butterfly reduction, then one atomic per (k,{A,V}) per wave.
    // All 4 waves of the block share the same b (block spans one h-chunk).
#pragma unroll
    for (int k = 0; k < K; ++k) {
        float a = accA[k], v = accV[k];
#pragma unroll
        for (int off = 32; off > 0; off >>= 1) {
            a += __shfl_xor(a, off);
            v += __shfl_xor(v, off);
        }
        if ((threadIdx.x & 63) == 0) {
            atomicAdd(&ws[b * K + k], a);
            atomicAdd(&ws[128 + b * K + k], v);
        }
    }
}

__global__ void ncuts_final(const float* __restrict__ ws,
                            const int* __restrict__ ncut_k,
                            float* __restrict__ out)
{
    const int t = threadIdx.x;        // 128 threads: t = b*16 + k
    const int b = t >> 4;
    const int k = t & 15;
    float r = ws[b * K + k] / ws[128 + b * K + k];
#pragma unroll
    for (int off = 1; off < 16; off <<= 1) r += __shfl_xor(r, off, 16);
    if (k == 0) out[b] = (float)(*ncut_k) - r;
}

extern "C" void kernel_launch(void* const* d_in, const int* in_sizes, int n_in,
                              void* d_out, int out_size, void* d_ws, size_t ws_size,
                              hipStream_t stream) {
    (void)in_sizes; (void)n_in; (void)out_size; (void)ws_size;
    const float* seg    = (const float*)d_in[0];
    const float* padded = (const float*)d_in[1];
    const float* weight = (const float*)d_in[2];
    const float* sumw   = (const float*)d_in[3];
    const int*   nk     = (const int*)d_in[5];
    float* ws  = (float*)d_ws;
    float* out = (float*)d_out;

    hipMemsetAsync(ws, 0, 2 * B * K * sizeof(float), stream);
    ncuts_main<<<NB, BLK, 0, stream>>>(seg, padded, weight, sumw, ws);
    ncuts_final<<<1, 128, 0, stream>>>(ws, nk, out);
}

// Round 3
// 452.274 us; speedup vs baseline: 1.3071x; 1.1205x over previous
//
#include <hip/hip_runtime.h>

#define B 8
#define K 16
#define H 224
#define W 224
#define PH 232
#define PW 232
#define WIN 9
#define WQ 56              // W / 4 pixels per quad-row
#define NQ (B * H * WQ)    // 100352 quads
#define BLK 256
#define NB (NQ / BLK)      // 392 blocks; 392/8 = 49 blocks per XCD chunk

// 4-float vector with only 4B alignment guarantee (weight rows are 4B-aligned)
typedef float vf4 __attribute__((ext_vector_type(4), aligned(4)));
typedef float vf4a __attribute__((ext_vector_type(4)));  // 16B-aligned

__global__ __launch_bounds__(BLK) void ncuts_main(
    const float* __restrict__ seg,      // [B][K][H][W]
    const float* __restrict__ padded,   // [B][K][PH][PW]
    const float* __restrict__ weight,   // [B][H][W][9][9]
    const float* __restrict__ sumw,     // [B][H][W]
    float* __restrict__ ws)             // ws[0..127]=A[b][k], ws[128..255]=V[b][k]
{
    // XCD-locality swizzle: block i -> XCD i%8; remap so XCD x owns batch b=x.
    const int qb = (blockIdx.x & 7) * (NB / 8) + (blockIdx.x >> 3);
    const int q  = qb * BLK + threadIdx.x;
    const int wq = q % WQ;
    const int t  = q / WQ;
    const int h  = t % H;
    const int b  = t / H;
    const int w0 = wq * 4;

    float acc[K][4];
#pragma unroll
    for (int k = 0; k < K; ++k)
#pragma unroll
        for (int p = 0; p < 4; ++p) acc[k][p] = 0.f;

    const long pixbase = ((long)(b * H + h)) * W + w0;          // pixel idx of p=0
    const float* wbase = weight + pixbase * 81;                 // 81 wts per pixel
    const float* pbase = padded + ((long)(b * K) * PH + h) * PW + w0;

    // m-loop kept rolled (9 iters) to bound code size; k,p,n fully unrolled.
#pragma unroll 1
    for (int m = 0; m < WIN; ++m) {
        // weight: zero-reuse stream -> nontemporal (evict-first), keeps L2 for padded
        float wr[4][WIN];
#pragma unroll
        for (int p = 0; p < 4; ++p) {
            const float* wp = wbase + (long)p * 81 + m * 9;
            vf4 wa = __builtin_nontemporal_load((const vf4*)wp);
            vf4 wb = __builtin_nontemporal_load((const vf4*)(wp + 4));
            float wc = __builtin_nontemporal_load(wp + 8);
            wr[p][0] = wa.x; wr[p][1] = wa.y; wr[p][2] = wa.z; wr[p][3] = wa.w;
            wr[p][4] = wb.x; wr[p][5] = wb.y; wr[p][6] = wb.z; wr[p][7] = wb.w;
            wr[p][8] = wc;
        }
        const float* prow = pbase + (long)m * PW;
#pragma unroll
        for (int k = 0; k < K; ++k) {
            const float4* pr = (const float4*)(prow + (long)k * PH * PW); // 16B aligned
            float4 a0 = pr[0], a1 = pr[1], a2 = pr[2];
            float win[12] = {a0.x, a0.y, a0.z, a0.w,
                             a1.x, a1.y, a1.z, a1.w,
                             a2.x, a2.y, a2.z, a2.w};
#pragma unroll
            for (int p = 0; p < 4; ++p)
#pragma unroll
                for (int n = 0; n < WIN; ++n)
                    acc[k][p] = fmaf(win[p + n], wr[p][n], acc[k][p]);
        }
    }

    // epilogue: assocA / assocV partials for this quad (seg/sumw: read-once -> nt)
    const vf4a sw4 = __builtin_nontemporal_load((const vf4a*)(sumw + pixbase));
    const float swv[4] = {sw4.x, sw4.y, sw4.z, sw4.w};
    const float* sbase = seg + ((long)(b * K) * H + h) * W + w0;

    float accA[K], accV[K];
#pragma unroll
    for (int k = 0; k < K; ++k) {
        const vf4a s4 = __builtin_nontemporal_load((const vf4a*)(sbase + (long)k * H * W));
        const float sv[4] = {s4.x, s4.y, s4.z, s4.w};
        float a = 0.f, v = 0.f;
#pragma unroll
        for (int p = 0; p < 4; ++p) {
            a = fmaf(acc[k][p], sv[p], a);
            v = fmaf(swv[p], sv[p], v);
        }
        accA[k] = a;
        accV[k] = v;
    }

    // per-wave butterfly reduction, then one atomic per (k,{A,V}) per wave.
#pragma unroll
    for (int k = 0; k < K; ++k) {
        float a = accA[k], v = accV[k];
#pragma unroll
        for (int off = 32; off > 0; off >>= 1) {
            a += __shfl_xor(a, off);
            v += __shfl_xor(v, off);
        }
        if ((threadIdx.x & 63) == 0) {
            atomicAdd(&ws[b * K + k], a);
            atomicAdd(&ws[128 + b * K + k], v);
        }
    }
}

__global__ void ncuts_final(const float* __restrict__ ws,
                            const int* __restrict__ ncut_k,
                            float* __restrict__ out)
{
    const int t = threadIdx.x;        // 128 threads: t = b*16 + k
    const int b = t >> 4;
    const int k = t & 15;
    float r = ws[b * K + k] / ws[128 + b * K + k];
#pragma unroll
    for (int off = 1; off < 16; off <<= 1) r += __shfl_xor(r, off, 16);
    if (k == 0) out[b] = (float)(*ncut_k) - r;
}

extern "C" void kernel_launch(void* const* d_in, const int* in_sizes, int n_in,
                              void* d_out, int out_size, void* d_ws, size_t ws_size,
                              hipStream_t stream) {
    (void)in_sizes; (void)n_in; (void)out_size; (void)ws_size;
    const float* seg    = (const float*)d_in[0];
    const float* padded = (const float*)d_in[1];
    const float* weight = (const float*)d_in[2];
    const float* sumw   = (const float*)d_in[3];
    const int*   nk     = (const int*)d_in[5];
    float* ws  = (float*)d_ws;
    float* out = (float*)d_out;

    hipMemsetAsync(ws, 0, 2 * B * K * sizeof(float), stream);
    ncuts_main<<<NB, BLK, 0, stream>>>(seg, padded, weight, sumw, ws);
    ncuts_final<<<1, 128, 0, stream>>>(ws, nk, out);
}